// Round 10
// baseline (18.983 us; speedup 1.0000x reference)
//
#include <hip/hip_runtime.h>

// LocalLinearLayer, SINGLE dispatch, software-pipelined 2 batches/block.
// out[b,o,c] = bias[o] + sum_{j=0..24} W[o, o+j] * xp[b, o+j, c]
// xp[q] = x[q] (q<12), x[q-12] (12<=q<4108), x[q-24] (q>=4108)
//
// Per 16-output tile at o0, kappa in [0,64):
//   out[o0+m'][c] = sum_kappa A[m'][kappa] * B[kappa][c]
//   A[m'][kappa]  = W[o0+m', kappa-m'] (0<=kappa-m'<25 else 0)
//   B[kappa][c]   = xp[o0+kappa][c]
// Block = (tile of 128 outputs) x (2 batches b0,b1). Schedule:
//   stage W rows -> LDS (f32, coalesced)
//   issue x loads for b0 AND b1 (regs); pack/write b0 -> x_lds[0]
//   barrier; gather A-fragments (once, reused for both batches)
//   compute+store b0        [b1 loads arriving under this]
//   pack/write b1 -> x_lds[1]
//   barrier; compute+store b1   [b0 stores draining under this]
// Keeps the HBM read pipe busy through the compute phases instead of the
// R9 lockstep read->compute->write phase structure.

typedef __attribute__((ext_vector_type(8))) short short8;
typedef __attribute__((ext_vector_type(4))) float f32x4;

constexpr int Lseq = 4096;
constexpr int C    = 64;
constexpr int WIN  = 25;
constexpr int PAD  = 12;
constexpr int O_B  = 128;          // outputs per block (4 waves x 2 tiles x 16)
constexpr int PWIN = 176;          // taps staged (128 + 48 halo)
constexpr int PLX  = 184;          // x_lds row stride (shorts); non-pow2 bank spread
constexpr int WROW = 28;           // w_band row stride (floats)
constexpr int NB   = 32;

__device__ __forceinline__ ushort f2bf(float f) {
    union { float f; uint u; } v; v.f = f;
    uint r = v.u + 0x7FFFu + ((v.u >> 16) & 1u);   // round-to-nearest-even
    return (ushort)(r >> 16);
}

__device__ __forceinline__ int tap_to_t(int q) {
    int t = (q < PAD) ? q : ((q < Lseq + PAD) ? q - PAD : q - 2 * PAD);
    return t > Lseq - 1 ? Lseq - 1 : t;   // clamped taps always meet zero weights
}

__device__ __forceinline__ void pack_write(const float4 f[2][8], bool has2,
                                           ushort* xl, int tid) {
#pragma unroll
    for (int s = 0; s < 2; ++s) {
        if (s == 1 && !has2) break;
        const int u = tid + 256 * s;
        const int c4 = u & 15, oct = u >> 4, p0 = oct * 8;
#pragma unroll
        for (int ch = 0; ch < 4; ++ch) {
            short8 pk;
#pragma unroll
            for (int i = 0; i < 8; ++i) {
                const float v = (ch == 0) ? f[s][i].x : (ch == 1) ? f[s][i].y
                              : (ch == 2) ? f[s][i].z : f[s][i].w;
                pk[i] = (short)f2bf(v);
            }
            *(short8*)&xl[(c4 * 4 + ch) * PLX + p0] = pk;
        }
    }
}

__device__ __forceinline__ void compute_store(const ushort* __restrict__ xl,
                                              const short8 af[2][2],
                                              const float* __restrict__ bias,
                                              float* __restrict__ ob,
                                              int blk_o, int w, int m, int quad) {
#pragma unroll
    for (int it = 0; it < 2; ++it) {
        const int t16 = w * 2 + it;
        const int o0  = blk_o + t16 * 16;

        f32x4 acc[4];
        {
            const float4 bv = *((const float4*)(bias + o0) + quad);
            const float bb[4] = {bv.x, bv.y, bv.z, bv.w};
#pragma unroll
            for (int r = 0; r < 4; ++r)
#pragma unroll
                for (int g = 0; g < 4; ++g) acc[g][r] = bb[r];
        }

#pragma unroll
        for (int cch = 0; cch < 2; ++cch) {
            const int poff = t16 * 16 + cch * 32 + quad * 8;
#pragma unroll
            for (int g = 0; g < 4; ++g) {
                short8 bf = *(const short8*)&xl[(m + 16 * g) * PLX + poff];
                acc[g] = __builtin_amdgcn_mfma_f32_16x16x32_bf16(af[it][cch], bf,
                                                                 acc[g], 0, 0, 0);
            }
        }

#pragma unroll
        for (int g = 0; g < 4; ++g)
#pragma unroll
            for (int r = 0; r < 4; ++r)
                ob[(size_t)(o0 + quad * 4 + r) * C + m + 16 * g] = acc[g][r];
    }
}

__global__ __launch_bounds__(256) void lll_db(const float* __restrict__ x,
                                              const float* __restrict__ W,
                                              const float* __restrict__ bias,
                                              float* __restrict__ out) {
    __shared__ ushort x_lds[2][C * PLX];     // 2 x 23.0 KB
    __shared__ float  w_band[O_B * WROW];    // 14.0 KB   (total ~60 KB -> 2 blocks/CU)

    const int bid   = blockIdx.x;
    const int tile  = bid >> 4;              // bid+16 = adjacent tile, same XCD slot
    const int pr    = bid & 15;
    const int b0    = pr;
    const int b1    = pr + 16;
    const int blk_o = tile * O_B;

    const int tid  = threadIdx.x;
    const int lane = tid & 63;
    const int w    = tid >> 6;
    const int m    = lane & 15;
    const int quad = lane >> 4;

    // ---- stage W band rows -> LDS, f32, 2 threads/row ----
    {
        const int row = tid >> 1, h = tid & 1;
        const float* wr = W + (size_t)(blk_o + row) * 4121 + h * 12;
        float v[13];
#pragma unroll
        for (int i = 0; i < 13; ++i) v[i] = wr[i];
        float* dst = &w_band[row * WROW + h * 12];
#pragma unroll
        for (int i = 0; i < 13; ++i) dst[i] = v[i];
    }

    // ---- issue x loads for BOTH batches; pack/write b0 ----
    const bool has2 = tid < 16 * (PWIN / 8) - 256;   // 352 units total
    const float4* xb0 = (const float4*)(x + (size_t)b0 * Lseq * C);
    const float4* xb1 = (const float4*)(x + (size_t)b1 * Lseq * C);

    float4 fA[2][8], fB[2][8];
#pragma unroll
    for (int s = 0; s < 2; ++s) {
        if (s == 1 && !has2) break;
        const int u = tid + 256 * s;
        const int c4 = u & 15, oct = u >> 4, p0 = oct * 8;
#pragma unroll
        for (int i = 0; i < 8; ++i) {
            const size_t off = (size_t)tap_to_t(blk_o + p0 + i) * 16 + c4;
            fA[s][i] = xb0[off];
            fB[s][i] = xb1[off];
        }
    }
    pack_write(fA, has2, &x_lds[0][0], tid);
    __syncthreads();

    // ---- gather A-fragments from w_band (once; reused for both batches) ----
    short8 afrag[2][2];
#pragma unroll
    for (int it = 0; it < 2; ++it) {
        const int row = (w * 2 + it) * 16 + m;
#pragma unroll
        for (int cch = 0; cch < 2; ++cch) {
            const int j0 = cch * 32 + quad * 8 - m;
            short8 pk;
#pragma unroll
            for (int e = 0; e < 8; ++e) {
                const int j  = j0 + e;
                const int jc = min(max(j, 0), WIN - 1);
                const float f = w_band[row * WROW + jc];
                pk[e] = (short)f2bf((j == jc) ? f : 0.f);
            }
            afrag[it][cch] = pk;
        }
    }

    // ---- batch 0: compute + store (b1 loads arriving underneath) ----
    compute_store(&x_lds[0][0], afrag, bias,
                  out + (size_t)b0 * Lseq * C, blk_o, w, m, quad);

    // ---- batch 1: write LDS, barrier, compute + store ----
    pack_write(fB, has2, &x_lds[1][0], tid);
    __syncthreads();
    compute_store(&x_lds[1][0], afrag, bias,
                  out + (size_t)b1 * Lseq * C, blk_o, w, m, quad);
}

extern "C" void kernel_launch(void* const* d_in, const int* in_sizes, int n_in,
                              void* d_out, int out_size, void* d_ws, size_t ws_size,
                              hipStream_t stream) {
    const float* x    = (const float*)d_in[0];
    const float* W    = (const float*)d_in[1];
    const float* bias = (const float*)d_in[2];
    float*       out  = (float*)d_out;

    lll_db<<<(Lseq / O_B) * (NB / 2), 256, 0, stream>>>(x, W, bias, out);  // 512 blocks
}

// Round 11
// 18.404 us; speedup vs baseline: 1.0315x; 1.0315x over previous
//
#include <hip/hip_runtime.h>

// LocalLinearLayer, SINGLE dispatch, O_B=64 for high occupancy (7 blocks/CU).
// out[b,o,c] = bias[o] + sum_{j=0..24} W[o, o+j] * xp[b, o+j, c]
// xp[q] = x[q] (q<12), x[q-12] (12<=q<4108), x[q-24] (q>=4108)
//
// Per 16-output tile at o0, kappa in [0,64):
//   out[o0+m'][c] = sum_kappa A[m'][kappa] * B[kappa][c]
//   A[m'][kappa]  = W[o0+m', kappa-m'] (0<=kappa-m'<25 else 0)
//   B[kappa][c]   = xp[o0+kappa][c]
// Block = 64 outputs (4 waves x 1 tile), one batch. W band staged f32 -> LDS
// (coalesced, 2 threads/row); lanes gather+pack A-fragments in registers.
// x staged bf16 [ch][tap] via b128 LDS writes. One barrier.

typedef __attribute__((ext_vector_type(8))) short short8;
typedef __attribute__((ext_vector_type(4))) float f32x4;

constexpr int Lseq = 4096;
constexpr int C    = 64;
constexpr int WIN  = 25;
constexpr int PAD  = 12;
constexpr int O_B  = 64;           // outputs per block (4 waves x 16)
constexpr int PWIN = 112;          // taps staged (64 + 48 halo)
constexpr int PLX  = 120;          // x_lds row stride (shorts); 15x16B segs -> 2-way-free
constexpr int WROW = 26;           // w_band row stride (floats)
constexpr int NB   = 32;

__device__ __forceinline__ ushort f2bf(float f) {
    union { float f; uint u; } v; v.f = f;
    uint r = v.u + 0x7FFFu + ((v.u >> 16) & 1u);   // round-to-nearest-even
    return (ushort)(r >> 16);
}

__device__ __forceinline__ int tap_to_t(int q) {
    int t = (q < PAD) ? q : ((q < Lseq + PAD) ? q - PAD : q - 2 * PAD);
    return t > Lseq - 1 ? Lseq - 1 : t;   // clamped taps always meet zero weights
}

__global__ __launch_bounds__(256) void lll_one(const float* __restrict__ x,
                                               const float* __restrict__ W,
                                               const float* __restrict__ bias,
                                               float* __restrict__ out) {
    __shared__ ushort x_lds[C * PLX];        // 15.0 KB: x bf16, [channel][tap]
    __shared__ float  w_band[O_B * WROW];    // 6.5 KB: raw band rows, f32

    const int bid   = blockIdx.x;
    const int tile  = bid >> 5;              // tile-major: bid+-32 = adjacent tile,
    const int b     = bid & 31;              //  same XCD slot (halo + W-band L2 reuse)
    const int blk_o = tile * O_B;

    const int tid  = threadIdx.x;
    const int lane = tid & 63;
    const int w    = tid >> 6;               // wave = 16-output tile
    const int m    = lane & 15;
    const int quad = lane >> 4;

    // ---- issue x global loads FIRST (HBM-critical stream) ----
    const bool hasx = tid < 16 * (PWIN / 8);           // 224 units: (c4, tap-oct)
    const int c4 = tid & 15, p0 = (tid >> 4) * 8;
    const float4* xb = (const float4*)(x + (size_t)b * Lseq * C);
    float4 f[8];
    if (hasx) {
#pragma unroll
        for (int i = 0; i < 8; ++i)
            f[i] = xb[(size_t)tap_to_t(blk_o + p0 + i) * 16 + c4];
    }

    // ---- stage W band rows -> LDS f32, 2 threads/row (L2-resident source) ----
    if (tid < 2 * O_B) {
        const int row = tid >> 1, h = tid & 1;
        const float* wr = W + (size_t)(blk_o + row) * 4121 + h * 12;
        float v[13];
#pragma unroll
        for (int i = 0; i < 13; ++i) v[i] = wr[i];
        float* dst = &w_band[row * WROW + h * 12];
#pragma unroll
        for (int i = 0; i < 13; ++i) dst[i] = v[i];
    }

    // ---- pack x -> bf16, b128 LDS writes ----
    if (hasx) {
#pragma unroll
        for (int ch = 0; ch < 4; ++ch) {
            short8 pk;
#pragma unroll
            for (int i = 0; i < 8; ++i) {
                const float v = (ch == 0) ? f[i].x : (ch == 1) ? f[i].y
                              : (ch == 2) ? f[i].z : f[i].w;
                pk[i] = (short)f2bf(v);
            }
            *(short8*)&x_lds[(c4 * 4 + ch) * PLX + p0] = pk;
        }
    }
    __syncthreads();

    // ---- gather A-fragment from w_band (1 tile per wave) ----
    short8 afrag[2];
    {
        const int row = w * 16 + m;                    // relative band row
#pragma unroll
        for (int cch = 0; cch < 2; ++cch) {
            const int j0 = cch * 32 + quad * 8 - m;
            short8 pk;
#pragma unroll
            for (int e = 0; e < 8; ++e) {
                const int j  = j0 + e;
                const int jc = min(max(j, 0), WIN - 1);
                const float g = w_band[row * WROW + jc];
                pk[e] = (short)f2bf((j == jc) ? g : 0.f);
            }
            afrag[cch] = pk;
        }
    }

    // ---- compute: 8 MFMAs, store ----
    const int o0 = blk_o + w * 16;
    f32x4 acc[4];
    {
        const float4 bv = *((const float4*)(bias + o0) + quad);
        const float bb[4] = {bv.x, bv.y, bv.z, bv.w};
#pragma unroll
        for (int r = 0; r < 4; ++r)
#pragma unroll
            for (int g = 0; g < 4; ++g) acc[g][r] = bb[r];
    }

#pragma unroll
    for (int cch = 0; cch < 2; ++cch) {
        const int poff = w * 16 + cch * 32 + quad * 8;
#pragma unroll
        for (int g = 0; g < 4; ++g) {
            short8 bf = *(const short8*)&x_lds[(m + 16 * g) * PLX + poff];
            acc[g] = __builtin_amdgcn_mfma_f32_16x16x32_bf16(afrag[cch], bf,
                                                             acc[g], 0, 0, 0);
        }
    }

    float* ob = out + (size_t)b * Lseq * C;
#pragma unroll
    for (int g = 0; g < 4; ++g)
#pragma unroll
        for (int r = 0; r < 4; ++r)
            ob[(size_t)(o0 + quad * 4 + r) * C + m + 16 * g] = acc[g][r];
}

extern "C" void kernel_launch(void* const* d_in, const int* in_sizes, int n_in,
                              void* d_out, int out_size, void* d_ws, size_t ws_size,
                              hipStream_t stream) {
    const float* x    = (const float*)d_in[0];
    const float* W    = (const float*)d_in[1];
    const float* bias = (const float*)d_in[2];
    float*       out  = (float*)d_out;

    lll_one<<<NB * (Lseq / O_B), 256, 0, stream>>>(x, W, bias, out);  // 2048 blocks
}